// Round 1
// baseline (1219.481 us; speedup 1.0000x reference)
//
#include <hip/hip_runtime.h>
#include <hip/hip_bf16.h>
#include <math.h>

#define BB 64
#define NN 16
#define HH 100
#define DD 400
#define AA 200
#define CATN 19
#define NODES 118            // HH + CATN-1
#define BN (BB*NODES)        // 7552
#define ATT_INV 0.07071067811865475f   // 1/sqrt(200)

// ---------------------------------------------------------------- concat he
__global__ __launch_bounds__(256) void k_concat_he(const float* __restrict__ hist,
    const float* __restrict__ proxy, float* __restrict__ he, int total) {
  int idx = blockIdx.x * 256 + threadIdx.x;
  if (idx >= total) return;
  int d = idx % DD;
  int bi = idx / DD;
  int i = bi % NODES;
  int b = bi / NODES;
  he[idx] = (i < HH) ? hist[((size_t)b * HH + i) * DD + d] : proxy[(size_t)(i - HH) * DD + d];
}

// ------------------------------------------------- tmp[b,i,:] = sum_j G[b,i,j] h[b,j,:]
__global__ __launch_bounds__(256) void k_graph_mm(const float* __restrict__ G,
    const float* __restrict__ h, float* __restrict__ out) {
  __shared__ float gl[8][NODES];
  const int b = blockIdx.y;
  const int i0 = blockIdx.x * 8;
  const int tid = threadIdx.x;
  for (int s = 0; s < 4; ++s) {
    int idx = tid + 256 * s;
    if (idx < 8 * NODES) {
      int r = idx / NODES, j = idx - r * NODES;
      gl[r][j] = (i0 + r < NODES) ? G[((size_t)b * NODES + i0 + r) * NODES + j] : 0.f;
    }
  }
  __syncthreads();
  const int c0 = tid;
  const int c1 = tid + 256;
  const bool has1 = (c1 < DD);
  float acc0[8], acc1[8];
#pragma unroll
  for (int r = 0; r < 8; ++r) { acc0[r] = 0.f; acc1[r] = 0.f; }
  for (int j = 0; j < NODES; ++j) {
    const float* hp = h + ((size_t)b * NODES + j) * DD;
    float v0 = hp[c0];
    float v1 = has1 ? hp[c1] : 0.f;
#pragma unroll
    for (int r = 0; r < 8; ++r) {
      acc0[r] += gl[r][j] * v0;
      acc1[r] += gl[r][j] * v1;
    }
  }
  for (int r = 0; r < 8; ++r) {
    int i = i0 + r;
    if (i < NODES) {
      size_t base = ((size_t)b * NODES + i) * DD;
      out[base + c0] = acc0[r];
      if (has1) out[base + c1] = acc1[r];
    }
  }
}

// ------------- h_out = LN(relu(in @ W + bias) + resid) * lns + lnb ; rows of 400
__global__ __launch_bounds__(256) void k_dense_ln(const float* __restrict__ in,
    const float* __restrict__ W, const float* __restrict__ bias,
    const float* __restrict__ resid, const float* __restrict__ lns,
    const float* __restrict__ lnb, float* __restrict__ out) {
  __shared__ float a_sh[16 * (DD + 1)];
  __shared__ float w_sh[16 * DD];
  const int tid = threadIdx.x;
  const size_t row0 = (size_t)blockIdx.x * 16;
  const int rl = tid >> 4;     // 0..15
  const int cl = tid & 15;     // 0..15
  for (int idx = tid; idx < 16 * DD; idx += 256) {
    int r = idx / DD, k = idx - r * DD;
    a_sh[r * (DD + 1) + k] = in[row0 * DD + idx];
  }
  __syncthreads();
  float acc[25];
#pragma unroll
  for (int i = 0; i < 25; ++i) acc[i] = 0.f;
  for (int k0 = 0; k0 < DD; k0 += 16) {
    for (int idx = tid; idx < 16 * DD; idx += 256)
      w_sh[idx] = W[(size_t)k0 * DD + idx];
    __syncthreads();
#pragma unroll
    for (int kk = 0; kk < 16; ++kk) {
      float av = a_sh[rl * (DD + 1) + k0 + kk];
#pragma unroll
      for (int cc = 0; cc < 25; ++cc)
        acc[cc] += av * w_sh[kk * DD + cl + 16 * cc];
    }
    __syncthreads();
  }
  const size_t rbase = (row0 + rl) * DD;
  float sum = 0.f;
#pragma unroll
  for (int cc = 0; cc < 25; ++cc) {
    int c = cl + 16 * cc;
    float z = acc[cc] + bias[c];
    z = fmaxf(z, 0.f) + resid[rbase + c];
    acc[cc] = z;
    sum += z;
  }
#pragma unroll
  for (int m = 1; m < 16; m <<= 1) sum += __shfl_xor(sum, m, 64);
  float mu = sum * (1.0f / DD);
  float vs = 0.f;
#pragma unroll
  for (int cc = 0; cc < 25; ++cc) { float d = acc[cc] - mu; vs += d * d; }
#pragma unroll
  for (int m = 1; m < 16; m <<= 1) vs += __shfl_xor(vs, m, 64);
  float rs = 1.0f / sqrtf(vs * (1.0f / DD) + 1e-5f);
#pragma unroll
  for (int cc = 0; cc < 25; ++cc) {
    int c = cl + 16 * cc;
    out[rbase + c] = (acc[cc] - mu) * rs * lns[c] + lnb[c];
  }
}

// ------------------------------- gf = h2[:, :HH] + he[:, :HH]
__global__ __launch_bounds__(256) void k_add_gf(const float* __restrict__ h2,
    const float* __restrict__ he, float* __restrict__ gf, int total) {
  int idx = blockIdx.x * 256 + threadIdx.x;
  if (idx >= total) return;
  int d = idx % DD;
  int bi = idx / DD;
  int i = bi % HH;
  int b = bi / HH;
  size_t src = ((size_t)b * NODES + i) * DD + d;
  gf[idx] = h2[src] + he[src];
}

// ------------------------------------------ generic GEMM: C = A[M,K] @ W[K,N] (+bias)
template<int KDIM, int NCOL, int CL, bool BIAS>
__global__ __launch_bounds__(256) void k_gemm(const float* __restrict__ A,
    const float* __restrict__ W, const float* __restrict__ bias, float* __restrict__ C) {
  constexpr int ROWS = 256 / CL;
  constexpr int CPT = NCOL / CL;
  constexpr int KT = (KDIM % 16 == 0) ? 16 : 8;
  __shared__ float a_sh[ROWS * (KDIM + 1)];
  __shared__ float w_sh[KT * NCOL];
  const int tid = threadIdx.x;
  const size_t row0 = (size_t)blockIdx.x * ROWS;
  const int rl = tid / CL;
  const int cl = tid % CL;
  for (int idx = tid; idx < ROWS * KDIM; idx += 256) {
    int r = idx / KDIM, k = idx - r * KDIM;
    a_sh[r * (KDIM + 1) + k] = A[row0 * KDIM + idx];
  }
  __syncthreads();
  float acc[CPT];
#pragma unroll
  for (int i = 0; i < CPT; ++i) acc[i] = 0.f;
  for (int k0 = 0; k0 < KDIM; k0 += KT) {
    for (int idx = tid; idx < KT * NCOL; idx += 256)
      w_sh[idx] = W[(size_t)k0 * NCOL + idx];
    __syncthreads();
#pragma unroll
    for (int kk = 0; kk < KT; ++kk) {
      float av = a_sh[rl * (KDIM + 1) + k0 + kk];
#pragma unroll
      for (int cc = 0; cc < CPT; ++cc)
        acc[cc] += av * w_sh[kk * NCOL + cl + CL * cc];
    }
    __syncthreads();
  }
  const size_t obase = (row0 + rl) * NCOL;
#pragma unroll
  for (int cc = 0; cc < CPT; ++cc) {
    int c = cl + CL * cc;
    float v = acc[cc];
    if (BIAS) v += bias[c];
    C[obase + c] = v;
  }
}

// ----------------------------- transpose icKw [D,A] -> [A,D]
__global__ __launch_bounds__(256) void k_transpose(const float* __restrict__ in,
    float* __restrict__ out) {
  int idx = blockIdx.x * 256 + threadIdx.x;
  if (idx >= AA * DD) return;
  int d = idx % DD, a = idx / DD;
  out[idx] = in[(size_t)d * AA + a];
}

// --------- a = K·Q/scale -> segment softmax by category -> alpha [B,N,H]
__global__ __launch_bounds__(128) void k_attn(const float* __restrict__ K,
    const float* __restrict__ Q, const int* __restrict__ cat, float* __restrict__ alpha) {
  __shared__ float q_sh[AA];
  __shared__ float a_sh[HH];
  __shared__ int c_sh[HH];
  __shared__ float smax[CATN], sden[CATN];
  const int bn = blockIdx.x;
  const int b = bn >> 4;     // N == 16
  const int tid = threadIdx.x;
  for (int idx = tid; idx < AA; idx += 128) q_sh[idx] = Q[(size_t)bn * AA + idx];
  if (tid < HH) c_sh[tid] = cat[b * HH + tid];
  __syncthreads();
  if (tid < HH) {
    const float* kp = K + ((size_t)b * HH + tid) * AA;
    float s = 0.f;
    for (int a = 0; a < AA; ++a) s += kp[a] * q_sh[a];
    a_sh[tid] = s * ATT_INV;
  }
  __syncthreads();
  if (tid < CATN) {
    float m = -3.4e38f;
    for (int h = 0; h < HH; ++h)
      if (c_sh[h] == tid) m = fmaxf(m, a_sh[h]);
    smax[tid] = m;
  }
  __syncthreads();
  if (tid < HH) a_sh[tid] = expf(a_sh[tid] - smax[c_sh[tid]]);
  __syncthreads();
  if (tid < CATN) {
    float dsum = 0.f;
    for (int h = 0; h < HH; ++h)
      if (c_sh[h] == tid) dsum += a_sh[h];
    sden[tid] = dsum;
  }
  __syncthreads();
  if (tid < HH) alpha[(size_t)bn * HH + tid] = a_sh[tid] / sden[c_sh[tid]];
}

// --------- intra[b,n,c,d] = sum_{h: cat[h]==c} alpha[b,n,h]*gf[b,h,d]
__global__ __launch_bounds__(256) void k_scatter(const float* __restrict__ alpha,
    const float* __restrict__ gf, const int* __restrict__ cat, float* __restrict__ intra) {
  __shared__ float acc_sh[CATN * DD];
  __shared__ float al_sh[HH];
  __shared__ int c_sh[HH];
  const int bn = blockIdx.x;
  const int b = bn >> 4;
  const int tid = threadIdx.x;
  for (int idx = tid; idx < CATN * DD; idx += 256) acc_sh[idx] = 0.f;
  if (tid < HH) {
    al_sh[tid] = alpha[(size_t)bn * HH + tid];
    c_sh[tid] = cat[b * HH + tid];
  }
  __syncthreads();
  const int c0 = tid;
  const int c1 = tid + 256;
  const bool has1 = (c1 < DD);
  for (int h = 0; h < HH; ++h) {
    float al = al_sh[h];
    int ct = c_sh[h];
    const float* gp = gf + ((size_t)b * HH + h) * DD;
    acc_sh[ct * DD + c0] += al * gp[c0];
    if (has1) acc_sh[ct * DD + c1] += al * gp[c1];
  }
  __syncthreads();
  for (int idx = tid; idx < CATN * DD; idx += 256)
    intra[(size_t)bn * CATN * DD + idx] = acc_sh[idx];
}

// --------- in-place: row = relu(row @ W + b) + row   (rows of 400)
__global__ __launch_bounds__(256) void k_affine(float* __restrict__ io,
    const float* __restrict__ W, const float* __restrict__ bias) {
  __shared__ float a_sh[16 * (DD + 1)];
  __shared__ float w_sh[16 * DD];
  const int tid = threadIdx.x;
  const size_t row0 = (size_t)blockIdx.x * 16;
  const int rl = tid >> 4;
  const int cl = tid & 15;
  for (int idx = tid; idx < 16 * DD; idx += 256) {
    int r = idx / DD, k = idx - r * DD;
    a_sh[r * (DD + 1) + k] = io[row0 * DD + idx];
  }
  __syncthreads();
  float acc[25];
#pragma unroll
  for (int i = 0; i < 25; ++i) acc[i] = 0.f;
  for (int k0 = 0; k0 < DD; k0 += 16) {
    for (int idx = tid; idx < 16 * DD; idx += 256)
      w_sh[idx] = W[(size_t)k0 * DD + idx];
    __syncthreads();
#pragma unroll
    for (int kk = 0; kk < 16; ++kk) {
      float av = a_sh[rl * (DD + 1) + k0 + kk];
#pragma unroll
      for (int cc = 0; cc < 25; ++cc)
        acc[cc] += av * w_sh[kk * DD + cl + 16 * cc];
    }
    __syncthreads();
  }
  const size_t rbase = (row0 + rl) * DD;
#pragma unroll
  for (int cc = 0; cc < 25; ++cc) {
    int c = cl + 16 * cc;
    float v = fmaxf(acc[cc] + bias[c], 0.f) + a_sh[rl * (DD + 1) + c];
    io[rbase + c] = v;
  }
}

// --------- s = intra·p/scale ; masked softmax over 19 ; out = sum_c w*intra
__global__ __launch_bounds__(256) void k_final(const float* __restrict__ intra,
    const float* __restrict__ p, const int* __restrict__ mask, float* __restrict__ out) {
  __shared__ float p_sh[DD];
  __shared__ float s_sh[CATN];
  __shared__ float w_sh[CATN];
  const int bn = blockIdx.x;
  const int b = bn >> 4;
  const int tid = threadIdx.x;
  for (int idx = tid; idx < DD; idx += 256) p_sh[idx] = p[(size_t)bn * DD + idx];
  __syncthreads();
  const int wv = tid >> 6, lane = tid & 63;
  const float* ib = intra + (size_t)bn * CATN * DD;
  for (int c = wv; c < CATN; c += 4) {
    float s = 0.f;
    for (int k = 0; k < 7; ++k) {
      int d = lane + 64 * k;
      if (d < DD) s += ib[(size_t)c * DD + d] * p_sh[d];
    }
#pragma unroll
    for (int m = 1; m < 64; m <<= 1) s += __shfl_xor(s, m, 64);
    if (lane == 0) s_sh[c] = s * ATT_INV;
  }
  __syncthreads();
  if (tid == 0) {
    float sv[CATN];
    float mx = -3.4e38f;
#pragma unroll
    for (int c = 0; c < CATN; ++c) {
      bool mk = (c == CATN - 1) || (mask[b * CATN + c] != 0);
      float s = mk ? s_sh[c] : -3.4e38f;
      sv[c] = s;
      mx = fmaxf(mx, s);
    }
    float den = 0.f;
#pragma unroll
    for (int c = 0; c < CATN; ++c) {
      float e = (sv[c] <= -3.3e38f) ? 0.f : expf(sv[c] - mx);
      w_sh[c] = e;
      den += e;
    }
    float inv = 1.0f / den;
#pragma unroll
    for (int c = 0; c < CATN; ++c) w_sh[c] *= inv;
  }
  __syncthreads();
  for (int d = tid; d < DD; d += 256) {
    float o = 0.f;
#pragma unroll
    for (int c = 0; c < CATN; ++c) o += w_sh[c] * ib[(size_t)c * DD + d];
    out[(size_t)bn * DD + d] = o;
  }
}

// ============================================================================
extern "C" void kernel_launch(void* const* d_in, const int* in_sizes, int n_in,
                              void* d_out, int out_size, void* d_ws, size_t ws_size,
                              hipStream_t stream) {
  const float* hist  = (const float*)d_in[0];
  const float* cand  = (const float*)d_in[1];
  const float* G     = (const float*)d_in[2];
  const int*   cmask = (const int*)d_in[3];
  const int*   cidx  = (const int*)d_in[4];
  const float* proxy = (const float*)d_in[5];
  const float* gW    = (const float*)d_in[6];
  const float* gb    = (const float*)d_in[7];
  const float* lns   = (const float*)d_in[8];
  const float* lnb   = (const float*)d_in[9];
  const float* Kw    = (const float*)d_in[10];
  const float* Qw    = (const float*)d_in[11];
  const float* Qbb   = (const float*)d_in[12];
  const float* afW   = (const float*)d_in[13];
  const float* afb   = (const float*)d_in[14];
  const float* icKw  = (const float*)d_in[15];
  const float* icQw  = (const float*)d_in[16];
  const float* icQb  = (const float*)d_in[17];
  float* out = (float*)d_out;
  float* ws  = (float*)d_ws;

  const size_t SLOT = (size_t)BN * DD;          // 3,020,800 floats
  float* he    = ws;                            // slot0: he (alive until add_gf)
  float* s1    = ws + SLOT;                     // slot1: h1, then gf
  float* s2    = ws + 2 * SLOT;                 // slot2: tmp, then K-proj
  float* s3    = ws + 3 * SLOT;                 // slot3: h2, then small bufs
  float* intra = ws + 4 * SLOT;                 // slot4: [B,N,C,D] 7,782,400 floats
  float* qbuf  = s3;                            // [B,N,A]   204,800
  float* qic   = s3 + 204800;                   // [B,N,A]   204,800
  float* icKwT = s3 + 409600;                   // [A,D]      80,000
  float* pbuf  = s3 + 489600;                   // [B,N,D]   409,600
  float* albuf = s3 + 899200;                   // [B,N,H]   102,400

  // 1. he = concat(history, proxy)
  k_concat_he<<<(BN * DD + 255) / 256, 256, 0, stream>>>(hist, proxy, he, BN * DD);
  // 2-3. GCN layer 0
  k_graph_mm<<<dim3(15, BB), 256, 0, stream>>>(G, he, s2);
  k_dense_ln<<<BN / 16, 256, 0, stream>>>(s2, gW, gb, he, lns, lnb, s1);
  // 4-5. GCN layer 1
  k_graph_mm<<<dim3(15, BB), 256, 0, stream>>>(G, s1, s2);
  k_dense_ln<<<BN / 16, 256, 0, stream>>>(s2, gW + DD * DD, gb + DD, s1, lns + DD, lnb + DD, s3);
  // 6. gf = (h2 + he)[:, :HH]  -> s1
  k_add_gf<<<(BB * HH * DD + 255) / 256, 256, 0, stream>>>(s3, he, s1, BB * HH * DD);
  // 7. K = gf @ Kw -> s2
  k_gemm<DD, AA, 8, false><<<BB * HH / 32, 256, 0, stream>>>(s1, Kw, nullptr, s2);
  // 8. Q = cand @ Qw + Qb
  k_gemm<DD, AA, 8, true><<<BB * NN / 32, 256, 0, stream>>>(cand, Qw, Qbb, qbuf);
  // 9. qic = cand @ icQw + icQb
  k_gemm<DD, AA, 8, true><<<BB * NN / 32, 256, 0, stream>>>(cand, icQw, icQb, qic);
  // 10. icKwT = icKw^T
  k_transpose<<<(AA * DD + 255) / 256, 256, 0, stream>>>(icKw, icKwT);
  // 11. p = qic @ icKwT   [B*N, D]
  k_gemm<AA, DD, 16, false><<<BB * NN / 16, 256, 0, stream>>>(qic, icKwT, nullptr, pbuf);
  // 12. alpha (segment softmax)
  k_attn<<<BB * NN, 128, 0, stream>>>(s2, qbuf, cidx, albuf);
  // 13. intra scatter
  k_scatter<<<BB * NN, 256, 0, stream>>>(albuf, s1, cidx, intra);
  // 14. intra = relu(intra @ afW + afb) + intra  (in-place)
  k_affine<<<BB * NN * CATN / 16, 256, 0, stream>>>(intra, afW, afb);
  // 15. inter-cluster softmax + weighted sum -> out
  k_final<<<BB * NN, 256, 0, stream>>>(intra, pbuf, cmask, out);
}

// Round 2
// 771.120 us; speedup vs baseline: 1.5814x; 1.5814x over previous
//
#include <hip/hip_runtime.h>
#include <hip/hip_bf16.h>
#include <math.h>

#define BB 64
#define NN 16
#define HH 100
#define DD 400
#define AA 200
#define CATN 19
#define NODES 118            // HH + CATN-1
#define BN (BB*NODES)        // 7552
#define ATT_INV 0.07071067811865475f   // 1/sqrt(200)
#define KPAD 416
#define APITCH 424

typedef __attribute__((ext_vector_type(4))) float f32x4;
typedef __attribute__((ext_vector_type(8))) short s16x8;

__device__ __forceinline__ unsigned short f2bf(float f) {
  union { float f; unsigned int u; } v; v.f = f;
  unsigned int r = v.u + 0x7FFFu + ((v.u >> 16) & 1u);
  return (unsigned short)(r >> 16);
}

// ---------------------------------------------------------------- concat he
__global__ __launch_bounds__(256) void k_concat_he(const float* __restrict__ hist,
    const float* __restrict__ proxy, float* __restrict__ he, int total) {
  int idx = blockIdx.x * 256 + threadIdx.x;
  if (idx >= total) return;
  int d = idx % DD;
  int bi = idx / DD;
  int i = bi % NODES;
  int b = bi / NODES;
  he[idx] = (i < HH) ? hist[((size_t)b * HH + i) * DD + d] : proxy[(size_t)(i - HH) * DD + d];
}

// ------------------------------------------------- tmp[b,i,:] = sum_j G[b,i,j] h[b,j,:]
__global__ __launch_bounds__(256) void k_graph_mm(const float* __restrict__ G,
    const float* __restrict__ h, float* __restrict__ out) {
  __shared__ float gl[8][NODES];
  const int b = blockIdx.y;
  const int i0 = blockIdx.x * 8;
  const int tid = threadIdx.x;
  for (int s = 0; s < 4; ++s) {
    int idx = tid + 256 * s;
    if (idx < 8 * NODES) {
      int r = idx / NODES, j = idx - r * NODES;
      gl[r][j] = (i0 + r < NODES) ? G[((size_t)b * NODES + i0 + r) * NODES + j] : 0.f;
    }
  }
  __syncthreads();
  const int c0 = tid;
  const int c1 = tid + 256;
  const bool has1 = (c1 < DD);
  float acc0[8], acc1[8];
#pragma unroll
  for (int r = 0; r < 8; ++r) { acc0[r] = 0.f; acc1[r] = 0.f; }
  for (int j = 0; j < NODES; ++j) {
    const float* hp = h + ((size_t)b * NODES + j) * DD;
    float v0 = hp[c0];
    float v1 = has1 ? hp[c1] : 0.f;
#pragma unroll
    for (int r = 0; r < 8; ++r) {
      acc0[r] += gl[r][j] * v0;
      acc1[r] += gl[r][j] * v1;
    }
  }
  for (int r = 0; r < 8; ++r) {
    int i = i0 + r;
    if (i < NODES) {
      size_t base = ((size_t)b * NODES + i) * DD;
      out[base + c0] = acc0[r];
      if (has1) out[base + c1] = acc1[r];
    }
  }
}

// ------------------------------- gf = h2[:, :HH] + he[:, :HH]
__global__ __launch_bounds__(256) void k_add_gf(const float* __restrict__ h2,
    const float* __restrict__ he, float* __restrict__ gf, int total) {
  int idx = blockIdx.x * 256 + threadIdx.x;
  if (idx >= total) return;
  int d = idx % DD;
  int bi = idx / DD;
  int i = bi % HH;
  int b = bi / HH;
  size_t src = ((size_t)b * NODES + i) * DD + d;
  gf[idx] = h2[src] + he[src];
}

// ---------------- weight prep: W[400][nout] fp32 -> Wt[npad][416] bf16 (transposed, padded)
__global__ __launch_bounds__(256) void k_prep_wt(const float* __restrict__ W,
    unsigned short* __restrict__ Wt, int nout, int npad) {
  int idx = blockIdx.x * 256 + threadIdx.x;
  if (idx >= npad * KPAD) return;
  int n = idx / KPAD, k = idx - n * KPAD;
  Wt[idx] = (k < DD && n < nout) ? f2bf(W[(size_t)k * nout + n]) : (unsigned short)0;
}

// =================== MFMA GEMM: C[M,NOUT] = A[M,400] @ W[400,NOUT] (bf16 in, fp32 acc)
// EPI: 0 = plain, 1 = +bias, 2 = relu(x+bias)+resid (affine), 3 = LN(relu(x+bias)+resid)
// A layout [M][400] fp32; Wt layout [NPAD][416] bf16 (transposed). M must be mult of 64.
template<int NFRAG, int NOUT, int EPI>
__global__ __launch_bounds__(256) void k_mg(
    const float* __restrict__ A, const unsigned short* __restrict__ Wt,
    const float* __restrict__ bias, const float* __restrict__ resid,
    const float* __restrict__ lns, const float* __restrict__ lnb,
    float* __restrict__ out) {
  __shared__ unsigned short a_sh[64 * APITCH];
  const int tid = threadIdx.x;
  const size_t row0 = (size_t)blockIdx.x * 64;
  // stage A tile: fp32 -> bf16, pitch APITCH
  for (int i = tid; i < 64 * 100; i += 256) {
    int r = i / 100, c4 = i - r * 100;
    const float4 v = *reinterpret_cast<const float4*>(&A[(row0 + r) * DD + c4 * 4]);
    unsigned int lo = (unsigned int)f2bf(v.x) | ((unsigned int)f2bf(v.y) << 16);
    unsigned int hi = (unsigned int)f2bf(v.z) | ((unsigned int)f2bf(v.w) << 16);
    *reinterpret_cast<uint2*>(&a_sh[r * APITCH + c4 * 4]) = make_uint2(lo, hi);
  }
  for (int i = tid; i < 64 * 8; i += 256) {   // zero K-pad cols 400..415
    int r = i / 8, c = i - r * 8;
    *reinterpret_cast<unsigned int*>(&a_sh[r * APITCH + 400 + c * 2]) = 0u;
  }
  __syncthreads();
  const int lane = tid & 63, w = tid >> 6;
  const int lrow = lane & 15, lk = lane >> 4;
  f32x4 acc[NFRAG];
#pragma unroll
  for (int c = 0; c < NFRAG; ++c) acc[c] = f32x4{0.f, 0.f, 0.f, 0.f};
  const unsigned short* ap = &a_sh[(w * 16 + lrow) * APITCH + lk * 8];
  const unsigned short* wp = &Wt[(size_t)lrow * KPAD + lk * 8];
  for (int ks = 0; ks < 13; ++ks) {
    s16x8 af = *reinterpret_cast<const s16x8*>(ap + ks * 32);
#pragma unroll
    for (int c = 0; c < NFRAG; ++c) {
      s16x8 bf = *reinterpret_cast<const s16x8*>(wp + (size_t)c * 16 * KPAD + ks * 32);
      acc[c] = __builtin_amdgcn_mfma_f32_16x16x32_bf16(af, bf, acc[c], 0, 0, 0);
    }
  }
  // C frag layout: col = c*16 + (lane&15), row = w*16 + (lane>>4)*4 + j
  const int r0 = w * 16 + lk * 4;
  if (EPI == 0 || EPI == 1) {
#pragma unroll
    for (int c = 0; c < NFRAG; ++c) {
      int col = c * 16 + lrow;
      if (col < NOUT) {
        float bv = (EPI == 1) ? bias[col] : 0.f;
#pragma unroll
        for (int j = 0; j < 4; ++j)
          out[(row0 + r0 + j) * NOUT + col] = acc[c][j] + bv;
      }
    }
  } else if (EPI == 2) {
#pragma unroll
    for (int c = 0; c < NFRAG; ++c) {
      int col = c * 16 + lrow;
      float bv = bias[col];
#pragma unroll
      for (int j = 0; j < 4; ++j) {
        size_t o = (row0 + r0 + j) * (size_t)DD + col;
        out[o] = fmaxf(acc[c][j] + bv, 0.f) + resid[o];
      }
    }
  } else {  // EPI == 3: z = relu(x+bias)+resid; out = LN(z)*lns + lnb
#pragma unroll
    for (int c = 0; c < NFRAG; ++c) {
      int col = c * 16 + lrow;
      float bv = bias[col];
#pragma unroll
      for (int j = 0; j < 4; ++j)
        acc[c][j] = fmaxf(acc[c][j] + bv, 0.f) + resid[(row0 + r0 + j) * (size_t)DD + col];
    }
    float mu[4], rs[4];
#pragma unroll
    for (int j = 0; j < 4; ++j) {
      float s = 0.f;
#pragma unroll
      for (int c = 0; c < NFRAG; ++c) s += acc[c][j];
      s += __shfl_xor(s, 1, 64); s += __shfl_xor(s, 2, 64);
      s += __shfl_xor(s, 4, 64); s += __shfl_xor(s, 8, 64);
      mu[j] = s * (1.0f / DD);
    }
#pragma unroll
    for (int j = 0; j < 4; ++j) {
      float v = 0.f;
#pragma unroll
      for (int c = 0; c < NFRAG; ++c) { float d = acc[c][j] - mu[j]; v += d * d; }
      v += __shfl_xor(v, 1, 64); v += __shfl_xor(v, 2, 64);
      v += __shfl_xor(v, 4, 64); v += __shfl_xor(v, 8, 64);
      rs[j] = 1.0f / sqrtf(v * (1.0f / DD) + 1e-5f);
    }
#pragma unroll
    for (int c = 0; c < NFRAG; ++c) {
      int col = c * 16 + lrow;
      float sc = lns[col], bo = lnb[col];
#pragma unroll
      for (int j = 0; j < 4; ++j)
        out[(row0 + r0 + j) * (size_t)DD + col] = (acc[c][j] - mu[j]) * rs[j] * sc + bo;
    }
  }
}

// ------------------------------------------ generic fp32 GEMM (kept for small pbuf gemm)
template<int KDIM, int NCOL, int CL, bool BIAS>
__global__ __launch_bounds__(256) void k_gemm(const float* __restrict__ A,
    const float* __restrict__ W, const float* __restrict__ bias, float* __restrict__ C) {
  constexpr int ROWS = 256 / CL;
  constexpr int CPT = NCOL / CL;
  constexpr int KT = (KDIM % 16 == 0) ? 16 : 8;
  __shared__ float a_sh[ROWS * (KDIM + 1)];
  __shared__ float w_sh[KT * NCOL];
  const int tid = threadIdx.x;
  const size_t row0 = (size_t)blockIdx.x * ROWS;
  const int rl = tid / CL;
  const int cl = tid % CL;
  for (int idx = tid; idx < ROWS * KDIM; idx += 256) {
    int r = idx / KDIM, k = idx - r * KDIM;
    a_sh[r * (KDIM + 1) + k] = A[row0 * KDIM + idx];
  }
  __syncthreads();
  float acc[CPT];
#pragma unroll
  for (int i = 0; i < CPT; ++i) acc[i] = 0.f;
  for (int k0 = 0; k0 < KDIM; k0 += KT) {
    for (int idx = tid; idx < KT * NCOL; idx += 256)
      w_sh[idx] = W[(size_t)k0 * NCOL + idx];
    __syncthreads();
#pragma unroll
    for (int kk = 0; kk < KT; ++kk) {
      float av = a_sh[rl * (KDIM + 1) + k0 + kk];
#pragma unroll
      for (int cc = 0; cc < CPT; ++cc)
        acc[cc] += av * w_sh[kk * NCOL + cl + CL * cc];
    }
    __syncthreads();
  }
  const size_t obase = (row0 + rl) * NCOL;
#pragma unroll
  for (int cc = 0; cc < CPT; ++cc) {
    int c = cl + CL * cc;
    float v = acc[cc];
    if (BIAS) v += bias[c];
    C[obase + c] = v;
  }
}

// ----------------------------- transpose icKw [D,A] -> [A,D] (fp32, for pbuf gemm)
__global__ __launch_bounds__(256) void k_transpose(const float* __restrict__ in,
    float* __restrict__ out) {
  int idx = blockIdx.x * 256 + threadIdx.x;
  if (idx >= AA * DD) return;
  int d = idx % DD, a = idx / DD;
  out[idx] = in[(size_t)d * AA + a];
}

// --------- a = K·Q/scale -> segment softmax by category -> alpha [B,N,H]
__global__ __launch_bounds__(128) void k_attn(const float* __restrict__ K,
    const float* __restrict__ Q, const int* __restrict__ cat, float* __restrict__ alpha) {
  __shared__ float q_sh[AA];
  __shared__ float a_sh[HH];
  __shared__ int c_sh[HH];
  __shared__ float smax[CATN], sden[CATN];
  const int bn = blockIdx.x;
  const int b = bn >> 4;     // N == 16
  const int tid = threadIdx.x;
  for (int idx = tid; idx < AA; idx += 128) q_sh[idx] = Q[(size_t)bn * AA + idx];
  if (tid < HH) c_sh[tid] = cat[b * HH + tid];
  __syncthreads();
  if (tid < HH) {
    const float* kp = K + ((size_t)b * HH + tid) * AA;
    float s = 0.f;
    for (int a = 0; a < AA; ++a) s += kp[a] * q_sh[a];
    a_sh[tid] = s * ATT_INV;
  }
  __syncthreads();
  if (tid < CATN) {
    float m = -3.4e38f;
    for (int h = 0; h < HH; ++h)
      if (c_sh[h] == tid) m = fmaxf(m, a_sh[h]);
    smax[tid] = m;
  }
  __syncthreads();
  if (tid < HH) a_sh[tid] = expf(a_sh[tid] - smax[c_sh[tid]]);
  __syncthreads();
  if (tid < CATN) {
    float dsum = 0.f;
    for (int h = 0; h < HH; ++h)
      if (c_sh[h] == tid) dsum += a_sh[h];
    sden[tid] = dsum;
  }
  __syncthreads();
  if (tid < HH) alpha[(size_t)bn * HH + tid] = a_sh[tid] / sden[c_sh[tid]];
}

// --------- intra[b,n,c,d] = sum_{h: cat[h]==c} alpha[b,n,h]*gf[b,h,d]
__global__ __launch_bounds__(256) void k_scatter(const float* __restrict__ alpha,
    const float* __restrict__ gf, const int* __restrict__ cat, float* __restrict__ intra) {
  __shared__ float acc_sh[CATN * DD];
  __shared__ float al_sh[HH];
  __shared__ int c_sh[HH];
  const int bn = blockIdx.x;
  const int b = bn >> 4;
  const int tid = threadIdx.x;
  for (int idx = tid; idx < CATN * DD; idx += 256) acc_sh[idx] = 0.f;
  if (tid < HH) {
    al_sh[tid] = alpha[(size_t)bn * HH + tid];
    c_sh[tid] = cat[b * HH + tid];
  }
  __syncthreads();
  const int c0 = tid;
  const int c1 = tid + 256;
  const bool has1 = (c1 < DD);
  for (int h = 0; h < HH; ++h) {
    float al = al_sh[h];
    int ct = c_sh[h];
    const float* gp = gf + ((size_t)b * HH + h) * DD;
    acc_sh[ct * DD + c0] += al * gp[c0];
    if (has1) acc_sh[ct * DD + c1] += al * gp[c1];
  }
  __syncthreads();
  for (int idx = tid; idx < CATN * DD; idx += 256)
    intra[(size_t)bn * CATN * DD + idx] = acc_sh[idx];
}

// --------- s = intra·p/scale ; masked softmax over 19 ; out = sum_c w*intra
__global__ __launch_bounds__(256) void k_final(const float* __restrict__ intra,
    const float* __restrict__ p, const int* __restrict__ mask, float* __restrict__ out) {
  __shared__ float p_sh[DD];
  __shared__ float s_sh[CATN];
  __shared__ float w_sh[CATN];
  const int bn = blockIdx.x;
  const int b = bn >> 4;
  const int tid = threadIdx.x;
  for (int idx = tid; idx < DD; idx += 256) p_sh[idx] = p[(size_t)bn * DD + idx];
  __syncthreads();
  const int wv = tid >> 6, lane = tid & 63;
  const float* ib = intra + (size_t)bn * CATN * DD;
  for (int c = wv; c < CATN; c += 4) {
    float s = 0.f;
    for (int k = 0; k < 7; ++k) {
      int d = lane + 64 * k;
      if (d < DD) s += ib[(size_t)c * DD + d] * p_sh[d];
    }
#pragma unroll
    for (int m = 1; m < 64; m <<= 1) s += __shfl_xor(s, m, 64);
    if (lane == 0) s_sh[c] = s * ATT_INV;
  }
  __syncthreads();
  if (tid == 0) {
    float sv[CATN];
    float mx = -3.4e38f;
#pragma unroll
    for (int c = 0; c < CATN; ++c) {
      bool mk = (c == CATN - 1) || (mask[b * CATN + c] != 0);
      float s = mk ? s_sh[c] : -3.4e38f;
      sv[c] = s;
      mx = fmaxf(mx, s);
    }
    float den = 0.f;
#pragma unroll
    for (int c = 0; c < CATN; ++c) {
      float e = (sv[c] <= -3.3e38f) ? 0.f : expf(sv[c] - mx);
      w_sh[c] = e;
      den += e;
    }
    float inv = 1.0f / den;
#pragma unroll
    for (int c = 0; c < CATN; ++c) w_sh[c] *= inv;
  }
  __syncthreads();
  for (int d = tid; d < DD; d += 256) {
    float o = 0.f;
#pragma unroll
    for (int c = 0; c < CATN; ++c) o += w_sh[c] * ib[(size_t)c * DD + d];
    out[(size_t)bn * DD + d] = o;
  }
}

// ============================================================================
extern "C" void kernel_launch(void* const* d_in, const int* in_sizes, int n_in,
                              void* d_out, int out_size, void* d_ws, size_t ws_size,
                              hipStream_t stream) {
  const float* hist  = (const float*)d_in[0];
  const float* cand  = (const float*)d_in[1];
  const float* G     = (const float*)d_in[2];
  const int*   cmask = (const int*)d_in[3];
  const int*   cidx  = (const int*)d_in[4];
  const float* proxy = (const float*)d_in[5];
  const float* gW    = (const float*)d_in[6];
  const float* gb    = (const float*)d_in[7];
  const float* lns   = (const float*)d_in[8];
  const float* lnb   = (const float*)d_in[9];
  const float* Kw    = (const float*)d_in[10];
  const float* Qw    = (const float*)d_in[11];
  const float* Qbb   = (const float*)d_in[12];
  const float* afW   = (const float*)d_in[13];
  const float* afb   = (const float*)d_in[14];
  const float* icKw  = (const float*)d_in[15];
  const float* icQw  = (const float*)d_in[16];
  const float* icQb  = (const float*)d_in[17];
  float* out = (float*)d_out;
  float* ws  = (float*)d_ws;

  const size_t SLOT = (size_t)BN * DD;          // 3,020,800 floats
  float* he    = ws;                            // slot0: he
  float* s1    = ws + SLOT;                     // slot1: h1 -> gf
  float* s2    = ws + 2 * SLOT;                 // slot2: graph tmp -> h2 (in-place LN) -> Kproj
  float* s3    = ws + 3 * SLOT;                 // slot3: small bufs + bf16 weights
  float* intra = ws + 4 * SLOT;                 // slot4: [B,N,C,D]
  float* qbuf  = s3;                            // [B,N,A]   204,800
  float* qic   = s3 + 204800;                   // [B,N,A]   204,800
  float* icKwT = s3 + 409600;                   // [A,D]      80,000
  float* pbuf  = s3 + 489600;                   // [B,N,D]   409,600
  float* albuf = s3 + 899200;                   // [B,N,H]   102,400
  unsigned short* gW0t  = (unsigned short*)(s3 + 1001600);  // 400x416
  unsigned short* gW1t  = gW0t + 166400;
  unsigned short* afWt  = gW1t + 166400;
  unsigned short* Kwt   = afWt + 166400;                    // 208x416
  unsigned short* Qwt   = Kwt + 86528;
  unsigned short* icQwt = Qwt + 86528;

  // 0. weight prep (bf16 transposed) + fp32 transpose for pbuf gemm
  k_prep_wt<<<650, 256, 0, stream>>>(gW, gW0t, DD, DD);
  k_prep_wt<<<650, 256, 0, stream>>>(gW + DD * DD, gW1t, DD, DD);
  k_prep_wt<<<650, 256, 0, stream>>>(afW, afWt, DD, DD);
  k_prep_wt<<<338, 256, 0, stream>>>(Kw, Kwt, AA, 208);
  k_prep_wt<<<338, 256, 0, stream>>>(Qw, Qwt, AA, 208);
  k_prep_wt<<<338, 256, 0, stream>>>(icQw, icQwt, AA, 208);
  k_transpose<<<(AA * DD + 255) / 256, 256, 0, stream>>>(icKw, icKwT);
  // 1. he = concat(history, proxy)
  k_concat_he<<<(BN * DD + 255) / 256, 256, 0, stream>>>(hist, proxy, he, BN * DD);
  // 2-3. GCN layer 0: tmp = G@he -> s2; h1 = LN(relu(tmp@W0+b0)+he) -> s1
  k_graph_mm<<<dim3(15, BB), 256, 0, stream>>>(G, he, s2);
  k_mg<25, 400, 3><<<BN / 64, 256, 0, stream>>>(s2, gW0t, gb, he, lns, lnb, s1);
  // 4-5. GCN layer 1 (LN in-place into s2)
  k_graph_mm<<<dim3(15, BB), 256, 0, stream>>>(G, s1, s2);
  k_mg<25, 400, 3><<<BN / 64, 256, 0, stream>>>(s2, gW1t, gb + DD, s1, lns + DD, lnb + DD, s2);
  // 6. gf = (h2 + he)[:, :HH] -> s1
  k_add_gf<<<(BB * HH * DD + 255) / 256, 256, 0, stream>>>(s2, he, s1, BB * HH * DD);
  // 7. K = gf @ Kw -> s2
  k_mg<13, 200, 0><<<BB * HH / 64, 256, 0, stream>>>(s1, Kwt, nullptr, nullptr, nullptr, nullptr, s2);
  // 8-9. Q = cand@Qw+Qb ; qic = cand@icQw+icQb
  k_mg<13, 200, 1><<<BB * NN / 64, 256, 0, stream>>>(cand, Qwt, Qbb, nullptr, nullptr, nullptr, qbuf);
  k_mg<13, 200, 1><<<BB * NN / 64, 256, 0, stream>>>(cand, icQwt, icQb, nullptr, nullptr, nullptr, qic);
  // 10. p = qic @ icKwT   [B*N, D]  (small fp32 gemm)
  k_gemm<AA, DD, 16, false><<<BB * NN / 16, 256, 0, stream>>>(qic, icKwT, nullptr, pbuf);
  // 11. alpha (segment softmax)
  k_attn<<<BB * NN, 128, 0, stream>>>(s2, qbuf, cidx, albuf);
  // 12. intra scatter
  k_scatter<<<BB * NN, 256, 0, stream>>>(albuf, s1, cidx, intra);
  // 13. intra = relu(intra @ afW + afb) + intra  (in-place, MFMA)
  k_mg<25, 400, 2><<<BB * NN * CATN / 64, 256, 0, stream>>>(intra, afWt, afb, intra, nullptr, nullptr, intra);
  // 14. inter-cluster softmax + weighted sum -> out
  k_final<<<BB * NN, 256, 0, stream>>>(intra, pbuf, cmask, out);
}

// Round 3
// 455.114 us; speedup vs baseline: 2.6795x; 1.6943x over previous
//
#include <hip/hip_runtime.h>
#include <hip/hip_bf16.h>
#include <math.h>

#define BB 64
#define NN 16
#define HH 100
#define DD 400
#define AA 200
#define CATN 19
#define NODES 118            // HH + CATN-1
#define BN (BB*NODES)        // 7552
#define BH (BB*HH)           // 6400
#define ATT_INV 0.07071067811865475f   // 1/sqrt(200)

typedef __attribute__((ext_vector_type(4))) float f32x4;
typedef __attribute__((ext_vector_type(8))) short s16x8;

__device__ __forceinline__ unsigned short f2bf(float f) {
  union { float f; unsigned int u; } v; v.f = f;
  unsigned int r = v.u + 0x7FFFu + ((v.u >> 16) & 1u);
  return (unsigned short)(r >> 16);
}

// ---------------------------------------------------------------- concat he
__global__ __launch_bounds__(256) void k_concat_he(const float* __restrict__ hist,
    const float* __restrict__ proxy, float* __restrict__ he, int total) {
  int idx = blockIdx.x * 256 + threadIdx.x;
  if (idx >= total) return;
  int d = idx % DD;
  int bi = idx / DD;
  int i = bi % NODES;
  int b = bi / NODES;
  he[idx] = (i < HH) ? hist[((size_t)b * HH + i) * DD + d] : proxy[(size_t)(i - HH) * DD + d];
}

// ------------------------------------------------- tmp[b,i,:] = sum_j G[b,i,j] h[b,j,:]
__global__ __launch_bounds__(256) void k_graph_mm(const float* __restrict__ G,
    const float* __restrict__ h, float* __restrict__ out) {
  __shared__ float gl[8][NODES];
  const int b = blockIdx.y;
  const int i0 = blockIdx.x * 8;
  const int tid = threadIdx.x;
  for (int s = 0; s < 4; ++s) {
    int idx = tid + 256 * s;
    if (idx < 8 * NODES) {
      int r = idx / NODES, j = idx - r * NODES;
      gl[r][j] = (i0 + r < NODES) ? G[((size_t)b * NODES + i0 + r) * NODES + j] : 0.f;
    }
  }
  __syncthreads();
  const int c0 = tid;
  const int c1 = tid + 256;
  const bool has1 = (c1 < DD);
  float acc0[8], acc1[8];
#pragma unroll
  for (int r = 0; r < 8; ++r) { acc0[r] = 0.f; acc1[r] = 0.f; }
  for (int j = 0; j < NODES; ++j) {
    const float* hp = h + ((size_t)b * NODES + j) * DD;
    float v0 = hp[c0];
    float v1 = has1 ? hp[c1] : 0.f;
#pragma unroll
    for (int r = 0; r < 8; ++r) {
      acc0[r] += gl[r][j] * v0;
      acc1[r] += gl[r][j] * v1;
    }
  }
  for (int r = 0; r < 8; ++r) {
    int i = i0 + r;
    if (i < NODES) {
      size_t base = ((size_t)b * NODES + i) * DD;
      out[base + c0] = acc0[r];
      if (has1) out[base + c1] = acc1[r];
    }
  }
}

// ------------------------------- gf[b*100+i] = h2[b*118+i] + he[b*118+i]  (compact)
__global__ __launch_bounds__(256) void k_add_gf(const float* __restrict__ h2,
    const float* __restrict__ he, float* __restrict__ gf, int total) {
  int idx = blockIdx.x * 256 + threadIdx.x;
  if (idx >= total) return;
  int d = idx % DD;
  int bi = idx / DD;
  int i = bi % HH;
  int b = bi / HH;
  size_t src = ((size_t)b * NODES + i) * DD + d;
  gf[idx] = h2[src] + he[src];
}

// ---------------- one-shot weight prep: all bf16 transposed+padded weight blobs
// layout (ushort offsets): gW0t@0 [416][416], gW1t@173056, afWt@346112,
// Kwt@519168 [224][416], Qqt@612352 [416][416], icKwB@785408 [416][224]; bias2 float[416]
__global__ __launch_bounds__(256) void k_prep_all(const float* __restrict__ gW,
    const float* __restrict__ afW, const float* __restrict__ Kw,
    const float* __restrict__ Qw, const float* __restrict__ icQw,
    const float* __restrict__ icKw, const float* __restrict__ Qb,
    const float* __restrict__ icQb, unsigned short* __restrict__ wbase,
    float* __restrict__ bias2) {
  int idx = blockIdx.x * 256 + threadIdx.x;
  const int SG = 416 * 416;   // 173056
  const int SK = 224 * 416;   // 93184
  if (idx < SG) {             // gW0t
    int n = idx / 416, k = idx - n * 416;
    wbase[idx] = (n < 400 && k < 400) ? f2bf(gW[(size_t)k * 400 + n]) : (unsigned short)0;
    return;
  }
  idx -= SG;
  if (idx < SG) {             // gW1t
    int n = idx / 416, k = idx - n * 416;
    wbase[173056 + idx] = (n < 400 && k < 400) ? f2bf(gW[160000 + (size_t)k * 400 + n]) : (unsigned short)0;
    return;
  }
  idx -= SG;
  if (idx < SG) {             // afWt
    int n = idx / 416, k = idx - n * 416;
    wbase[346112 + idx] = (n < 400 && k < 400) ? f2bf(afW[(size_t)k * 400 + n]) : (unsigned short)0;
    return;
  }
  idx -= SG;
  if (idx < SK) {             // Kwt [224 n][416 k]
    int n = idx / 416, k = idx - n * 416;
    wbase[519168 + idx] = (n < 200 && k < 400) ? f2bf(Kw[(size_t)k * 200 + n]) : (unsigned short)0;
    return;
  }
  idx -= SK;
  if (idx < SG) {             // Qqt [416 n][416 k]: n<200 -> Qw col n ; 208<=n<408 -> icQw col n-208
    int n = idx / 416, k = idx - n * 416;
    unsigned short v = 0;
    if (k < 400) {
      if (n < 200) v = f2bf(Qw[(size_t)k * 200 + n]);
      else if (n >= 208 && n < 408) v = f2bf(icQw[(size_t)k * 200 + (n - 208)]);
    }
    wbase[612352 + idx] = v;
    return;
  }
  idx -= SG;
  if (idx < SK) {             // icKwB [416 d][224 a]
    int d = idx / 224, a = idx - d * 224;
    wbase[785408 + idx] = (d < 400 && a < 200) ? f2bf(icKw[(size_t)d * 200 + a]) : (unsigned short)0;
    return;
  }
  idx -= SK;
  if (idx < 416) {            // bias2
    float v = 0.f;
    if (idx < 200) v = Qb[idx];
    else if (idx >= 208 && idx < 408) v = icQb[idx - 208];
    bias2[idx] = v;
  }
}

// =================== MFMA GEMM: C[M,NOUT] = A[M,KDIM] @ W[KDIM,NOUT] (bf16 in, fp32 acc)
// 32-row blocks, 4 waves: w&1 = row-group(16), w>>1 = N-half (NF0 frags each).
// Wt layout [NF0*32 rows][KPAD] (row-padded, zero-filled). M must be mult of 32.
// EPI: 0 plain(+colguard)  2 relu(x+b)+resid(in-place)  3 LN(relu(x+b)+resid)
//      5 dual-output: cols 0..199 -> out(+bias2), cols 208..407 -> out2(+bias2)
template<int KDIM, int KPAD, int NOUT, int EPI>
__global__ __launch_bounds__(256) void k_mg(
    const float* __restrict__ A, const unsigned short* __restrict__ Wt,
    const float* __restrict__ bias, const float* __restrict__ resid,
    const float* __restrict__ lns, const float* __restrict__ lnb,
    float* __restrict__ out, float* __restrict__ out2) {
  constexpr int APITCH = KPAD + 8;
  constexpr int NF = (NOUT + 15) / 16;
  constexpr int NF0 = (NF + 1) / 2;
  constexpr int KS = KPAD / 32;
  constexpr int E4 = KDIM / 4;
  constexpr int PADN = KPAD - KDIM;
  __shared__ unsigned short a_sh[32 * APITCH];
  __shared__ float ps_sh[32][2][2];
  const int tid = threadIdx.x;
  const size_t row0 = (size_t)blockIdx.x * 32;
  for (int i = tid; i < 32 * E4; i += 256) {
    int r = i / E4, c4 = i - r * E4;
    const float4 v = *reinterpret_cast<const float4*>(&A[(row0 + r) * (size_t)KDIM + c4 * 4]);
    unsigned int lo = (unsigned int)f2bf(v.x) | ((unsigned int)f2bf(v.y) << 16);
    unsigned int hi = (unsigned int)f2bf(v.z) | ((unsigned int)f2bf(v.w) << 16);
    *reinterpret_cast<uint2*>(&a_sh[r * APITCH + c4 * 4]) = make_uint2(lo, hi);
  }
  for (int i = tid; i < 32 * PADN; i += 256) {
    int r = i / PADN, c = i - r * PADN;
    a_sh[r * APITCH + KDIM + c] = 0;
  }
  __syncthreads();
  const int lane = tid & 63, w = tid >> 6;
  const int lrow = lane & 15, lk = lane >> 4;
  const int rg = w & 1, nh = w >> 1;
  const int cbeg = nh * NF0;
  f32x4 acc[NF0];
#pragma unroll
  for (int c = 0; c < NF0; ++c) acc[c] = f32x4{0.f, 0.f, 0.f, 0.f};
  const unsigned short* ap = &a_sh[(rg * 16 + lrow) * APITCH + lk * 8];
  const unsigned short* wp = &Wt[((size_t)(cbeg * 16) + lrow) * KPAD + lk * 8];
  for (int ks = 0; ks < KS; ++ks) {
    s16x8 af = *reinterpret_cast<const s16x8*>(ap + ks * 32);
#pragma unroll
    for (int c = 0; c < NF0; ++c) {
      s16x8 bf = *reinterpret_cast<const s16x8*>(wp + (size_t)c * 16 * KPAD + ks * 32);
      acc[c] = __builtin_amdgcn_mfma_f32_16x16x32_bf16(af, bf, acc[c], 0, 0, 0);
    }
  }
  // C frag: col = (cbeg+c)*16 + lrow, row = rg*16 + lk*4 + j
  const int r0 = rg * 16 + lk * 4;
  if (EPI == 0) {
#pragma unroll
    for (int c = 0; c < NF0; ++c) {
      int col = (cbeg + c) * 16 + lrow;
      if (col < NOUT) {
#pragma unroll
        for (int j = 0; j < 4; ++j)
          out[(row0 + r0 + j) * (size_t)NOUT + col] = acc[c][j];
      }
    }
  } else if (EPI == 2) {
#pragma unroll
    for (int c = 0; c < NF0; ++c) {
      int col = (cbeg + c) * 16 + lrow;
      if (col < NOUT) {
        float bv = bias[col];
#pragma unroll
        for (int j = 0; j < 4; ++j) {
          size_t o = (row0 + r0 + j) * (size_t)NOUT + col;
          out[o] = fmaxf(acc[c][j] + bv, 0.f) + resid[o];
        }
      }
    }
  } else if (EPI == 5) {
#pragma unroll
    for (int c = 0; c < NF0; ++c) {
      int col = (cbeg + c) * 16 + lrow;
      float bv = bias[col];
      if (col < 200) {
#pragma unroll
        for (int j = 0; j < 4; ++j)
          out[(row0 + r0 + j) * (size_t)AA + col] = acc[c][j] + bv;
      } else if (col >= 208 && col < 408) {
#pragma unroll
        for (int j = 0; j < 4; ++j)
          out2[(row0 + r0 + j) * (size_t)AA + (col - 208)] = acc[c][j] + bv;
      }
    }
  } else {  // EPI == 3: z = relu(x+bias)+resid; out = LN(z)*lns + lnb  (cross-wave reduce)
    float zs[4], zq[4];
#pragma unroll
    for (int j = 0; j < 4; ++j) { zs[j] = 0.f; zq[j] = 0.f; }
#pragma unroll
    for (int c = 0; c < NF0; ++c) {
      int col = (cbeg + c) * 16 + lrow;
      bool cv = col < NOUT;
      float bv = cv ? bias[col] : 0.f;
#pragma unroll
      for (int j = 0; j < 4; ++j) {
        float z = 0.f;
        if (cv)
          z = fmaxf(acc[c][j] + bv, 0.f) + resid[(row0 + r0 + j) * (size_t)NOUT + col];
        acc[c][j] = z;
        zs[j] += z;
        zq[j] += z * z;
      }
    }
#pragma unroll
    for (int j = 0; j < 4; ++j) {
      zs[j] += __shfl_xor(zs[j], 1, 64); zq[j] += __shfl_xor(zq[j], 1, 64);
      zs[j] += __shfl_xor(zs[j], 2, 64); zq[j] += __shfl_xor(zq[j], 2, 64);
      zs[j] += __shfl_xor(zs[j], 4, 64); zq[j] += __shfl_xor(zq[j], 4, 64);
      zs[j] += __shfl_xor(zs[j], 8, 64); zq[j] += __shfl_xor(zq[j], 8, 64);
    }
    if (lrow == 0) {
#pragma unroll
      for (int j = 0; j < 4; ++j) {
        ps_sh[r0 + j][nh][0] = zs[j];
        ps_sh[r0 + j][nh][1] = zq[j];
      }
    }
    __syncthreads();
    float mu[4], rs[4];
#pragma unroll
    for (int j = 0; j < 4; ++j) {
      float s = ps_sh[r0 + j][0][0] + ps_sh[r0 + j][1][0];
      float q = ps_sh[r0 + j][0][1] + ps_sh[r0 + j][1][1];
      mu[j] = s * (1.0f / NOUT);
      float var = q * (1.0f / NOUT) - mu[j] * mu[j];
      rs[j] = 1.0f / sqrtf(var + 1e-5f);
    }
#pragma unroll
    for (int c = 0; c < NF0; ++c) {
      int col = (cbeg + c) * 16 + lrow;
      if (col < NOUT) {
        float sc = lns[col], bo = lnb[col];
#pragma unroll
        for (int j = 0; j < 4; ++j)
          out[(row0 + r0 + j) * (size_t)NOUT + col] = (acc[c][j] - mu[j]) * rs[j] * sc + bo;
      }
    }
  }
}

// --------- fused: a = K·Q/scale -> segment softmax -> scatter into intra [B,N,C,D]
__global__ __launch_bounds__(256) void k_attsc(const float* __restrict__ K,
    const float* __restrict__ Q, const float* __restrict__ gf,
    const int* __restrict__ cat, float* __restrict__ intra) {
  __shared__ float q_sh[AA];
  __shared__ float a_sh[HH];
  __shared__ int c_sh[HH];
  __shared__ float smax[CATN], sden[CATN];
  __shared__ float acc_sh[CATN * DD];
  const int bn = blockIdx.x;
  const int b = bn >> 4;
  const int tid = threadIdx.x;
  for (int i = tid; i < CATN * DD; i += 256) acc_sh[i] = 0.f;
  if (tid < AA) q_sh[tid] = Q[(size_t)bn * AA + tid];
  if (tid < HH) c_sh[tid] = cat[b * HH + tid];
  __syncthreads();
  if (tid < 2 * HH) {
    int h = tid >> 1, half = tid & 1;
    const float* kp = K + ((size_t)b * HH + h) * AA + half * 100;
    const float* qp = q_sh + half * 100;
    float s = 0.f;
#pragma unroll 4
    for (int a = 0; a < 100; ++a) s += kp[a] * qp[a];
    s += __shfl_xor(s, 1, 64);
    if (half == 0) a_sh[h] = s * ATT_INV;
  }
  __syncthreads();
  if (tid < CATN) {
    float m = -3.4e38f;
    for (int h = 0; h < HH; ++h)
      if (c_sh[h] == tid) m = fmaxf(m, a_sh[h]);
    smax[tid] = m;
  }
  __syncthreads();
  if (tid < HH) a_sh[tid] = expf(a_sh[tid] - smax[c_sh[tid]]);
  __syncthreads();
  if (tid < CATN) {
    float dsum = 0.f;
    for (int h = 0; h < HH; ++h)
      if (c_sh[h] == tid) dsum += a_sh[h];
    sden[tid] = dsum;
  }
  __syncthreads();
  if (tid < HH) a_sh[tid] = a_sh[tid] / sden[c_sh[tid]];
  __syncthreads();
  const int c0 = tid;
  const int c1 = tid + 256;
  const bool has1 = (c1 < DD);
  for (int h = 0; h < HH; ++h) {
    float al = a_sh[h];
    int ct = c_sh[h];
    const float* gp = gf + ((size_t)b * HH + h) * DD;
    acc_sh[ct * DD + c0] += al * gp[c0];
    if (has1) acc_sh[ct * DD + c1] += al * gp[c1];
  }
  __syncthreads();
  for (int i = tid; i < CATN * DD; i += 256)
    intra[(size_t)bn * CATN * DD + i] = acc_sh[i];
}

// --------- s = intra·p/scale ; masked softmax over 19 ; out = sum_c w*intra
__global__ __launch_bounds__(256) void k_final(const float* __restrict__ intra,
    const float* __restrict__ p, const int* __restrict__ mask, float* __restrict__ out) {
  __shared__ float p_sh[DD];
  __shared__ float s_sh[CATN];
  __shared__ float w_sh[CATN];
  const int bn = blockIdx.x;
  const int b = bn >> 4;
  const int tid = threadIdx.x;
  for (int idx = tid; idx < DD; idx += 256) p_sh[idx] = p[(size_t)bn * DD + idx];
  __syncthreads();
  const int wv = tid >> 6, lane = tid & 63;
  const float* ib = intra + (size_t)bn * CATN * DD;
  for (int c = wv; c < CATN; c += 4) {
    float s = 0.f;
    for (int k = 0; k < 7; ++k) {
      int d = lane + 64 * k;
      if (d < DD) s += ib[(size_t)c * DD + d] * p_sh[d];
    }
#pragma unroll
    for (int m = 1; m < 64; m <<= 1) s += __shfl_xor(s, m, 64);
    if (lane == 0) s_sh[c] = s * ATT_INV;
  }
  __syncthreads();
  if (tid == 0) {
    float sv[CATN];
    float mx = -3.4e38f;
#pragma unroll
    for (int c = 0; c < CATN; ++c) {
      bool mk = (c == CATN - 1) || (mask[b * CATN + c] != 0);
      float s = mk ? s_sh[c] : -3.4e38f;
      sv[c] = s;
      mx = fmaxf(mx, s);
    }
    float den = 0.f;
#pragma unroll
    for (int c = 0; c < CATN; ++c) {
      float e = (sv[c] <= -3.3e38f) ? 0.f : expf(sv[c] - mx);
      w_sh[c] = e;
      den += e;
    }
    float inv = 1.0f / den;
#pragma unroll
    for (int c = 0; c < CATN; ++c) w_sh[c] *= inv;
  }
  __syncthreads();
  for (int d = tid; d < DD; d += 256) {
    float o = 0.f;
#pragma unroll
    for (int c = 0; c < CATN; ++c) o += w_sh[c] * ib[(size_t)c * DD + d];
    out[(size_t)bn * DD + d] = o;
  }
}

// ============================================================================
extern "C" void kernel_launch(void* const* d_in, const int* in_sizes, int n_in,
                              void* d_out, int out_size, void* d_ws, size_t ws_size,
                              hipStream_t stream) {
  const float* hist  = (const float*)d_in[0];
  const float* cand  = (const float*)d_in[1];
  const float* G     = (const float*)d_in[2];
  const int*   cmask = (const int*)d_in[3];
  const int*   cidx  = (const int*)d_in[4];
  const float* proxy = (const float*)d_in[5];
  const float* gW    = (const float*)d_in[6];
  const float* gb    = (const float*)d_in[7];
  const float* lns   = (const float*)d_in[8];
  const float* lnb   = (const float*)d_in[9];
  const float* Kw    = (const float*)d_in[10];
  const float* Qw    = (const float*)d_in[11];
  const float* Qbb   = (const float*)d_in[12];
  const float* afW   = (const float*)d_in[13];
  const float* afb   = (const float*)d_in[14];
  const float* icKw  = (const float*)d_in[15];
  const float* icQw  = (const float*)d_in[16];
  const float* icQb  = (const float*)d_in[17];
  float* out = (float*)d_out;
  float* ws  = (float*)d_ws;

  const size_t SLOT = (size_t)BN * DD;          // 3,020,800 floats
  float* he    = ws;                            // slot0: he (alive until add_gf)
  float* s1    = ws + SLOT;                     // slot1: h1 -> gf compact [6400][400]
  float* s2    = ws + 2 * SLOT;                 // slot2: graph tmp -> h2(in-place) -> K [6400][200]
  float* s3    = ws + 3 * SLOT;                 // slot3: small bufs + bf16 weights
  float* intra = ws + 4 * SLOT;                 // slot4: [B,N,C,D] 7,782,400 floats
  float* qbuf  = s3;                            // [1024][200]
  float* qic   = s3 + 204800;                   // [1024][200]
  float* pbuf  = s3 + 409600;                   // [1024][400]
  float* bias2 = s3 + 819200;                   // [416]
  unsigned short* wbase = (unsigned short*)(s3 + 819616);
  unsigned short* gW0t  = wbase;                // [416][416]
  unsigned short* gW1t  = wbase + 173056;
  unsigned short* afWt  = wbase + 346112;
  unsigned short* Kwt   = wbase + 519168;       // [224][416]
  unsigned short* Qqt   = wbase + 612352;       // [416][416]
  unsigned short* icKwB = wbase + 785408;       // [416][224]

  // 0. one-shot weight prep
  k_prep_all<<<3434, 256, 0, stream>>>(gW, afW, Kw, Qw, icQw, icKw, Qbb, icQb, wbase, bias2);
  // 1. he = concat(history, proxy)
  k_concat_he<<<(BN * DD + 255) / 256, 256, 0, stream>>>(hist, proxy, he, BN * DD);
  // 2-3. GCN layer 0: tmp = G@he -> s2; h1 = LN(relu(tmp@W0+b0)+he) -> s1
  k_graph_mm<<<dim3(15, BB), 256, 0, stream>>>(G, he, s2);
  k_mg<400, 416, 400, 3><<<BN / 32, 256, 0, stream>>>(s2, gW0t, gb, he, lns, lnb, s1, nullptr);
  // 4-5. GCN layer 1 (in-place -> s2 = h2)
  k_graph_mm<<<dim3(15, BB), 256, 0, stream>>>(G, s1, s2);
  k_mg<400, 416, 400, 3><<<BN / 32, 256, 0, stream>>>(s2, gW1t, gb + DD, s1, lns + DD, lnb + DD, s2, nullptr);
  // 6. gf = (h2 + he)[:, :HH] compact -> s1
  k_add_gf<<<(BH * DD + 255) / 256, 256, 0, stream>>>(s2, he, s1, BH * DD);
  // 7. K = gf @ Kw -> s2 [6400][200]
  k_mg<400, 416, 200, 0><<<BH / 32, 256, 0, stream>>>(s1, Kwt, nullptr, nullptr, nullptr, nullptr, s2, nullptr);
  // 8. dual projection: Q = cand@Qw+Qb -> qbuf ; qic = cand@icQw+icQb -> qic
  k_mg<400, 416, 416, 5><<<BB * NN / 32, 256, 0, stream>>>(cand, Qqt, bias2, nullptr, nullptr, nullptr, qbuf, qic);
  // 9. p = qic @ icKw^T -> pbuf [1024][400]
  k_mg<200, 224, 400, 0><<<BB * NN / 32, 256, 0, stream>>>(qic, icKwB, nullptr, nullptr, nullptr, nullptr, pbuf, nullptr);
  // 10. fused segment softmax + scatter -> intra
  k_attsc<<<BB * NN, 256, 0, stream>>>(s2, qbuf, s1, cidx, intra);
  // 11. intra = relu(intra @ afW + afb) + intra  (in-place, MFMA)
  k_mg<400, 416, 400, 2><<<BB * NN * CATN / 32, 256, 0, stream>>>(intra, afWt, afb, intra, nullptr, nullptr, intra, nullptr);
  // 12. inter-cluster softmax + weighted sum -> out
  k_final<<<BB * NN, 256, 0, stream>>>(intra, pbuf, cmask, out);
}

// Round 4
// 341.922 us; speedup vs baseline: 3.5665x; 1.3310x over previous
//
#include <hip/hip_runtime.h>
#include <hip/hip_bf16.h>
#include <math.h>

#define BB 64
#define NN 16
#define HH 100
#define DD 400
#define AA 200
#define CATN 19
#define NODES 118            // HH + CATN-1
#define BN (BB*NODES)        // 7552
#define BH (BB*HH)           // 6400
#define ATT_INV 0.07071067811865475f   // 1/sqrt(200)

typedef __attribute__((ext_vector_type(4))) float f32x4;
typedef __attribute__((ext_vector_type(8))) short s16x8;

__device__ __forceinline__ unsigned short f2bf(float f) {
  union { float f; unsigned int u; } v; v.f = f;
  unsigned int r = v.u + 0x7FFFu + ((v.u >> 16) & 1u);
  return (unsigned short)(r >> 16);
}

// ---------------------------------------------------------------- concat he
__global__ __launch_bounds__(256) void k_concat_he(const float* __restrict__ hist,
    const float* __restrict__ proxy, float* __restrict__ he, int total) {
  int idx = blockIdx.x * 256 + threadIdx.x;
  if (idx >= total) return;
  int d = idx % DD;
  int bi = idx / DD;
  int i = bi % NODES;
  int b = bi / NODES;
  he[idx] = (i < HH) ? hist[((size_t)b * HH + i) * DD + d] : proxy[(size_t)(i - HH) * DD + d];
}

// ---------------- transpose h[b][RPB][400] fp32 -> T[b][416][128] bf16 (j-padded)
template<int RPB>
__global__ __launch_bounds__(256) void k_toT(const float* __restrict__ h,
    unsigned short* __restrict__ T) {
  __shared__ float t_sh[64][129];
  const int b = blockIdx.x / 7, dt = blockIdx.x % 7;
  const int d0 = dt * 64;
  const int tid = threadIdx.x;
  const int dc = tid & 63, jr = tid >> 6;
  for (int j0 = 0; j0 < 128; j0 += 4) {
    int j = j0 + jr, d = d0 + dc;
    float v = (j < RPB && d < DD) ? h[((size_t)b * RPB + j) * DD + d] : 0.f;
    t_sh[dc][j] = v;
  }
  __syncthreads();
  const int jc = tid & 127, dr2 = tid >> 7;
  for (int di = 0; di < 64; di += 2) {
    int dr = di + dr2;
    int d = d0 + dr;
    if (d < 416) T[((size_t)b * 416 + d) * 128 + jc] = f2bf(t_sh[dr][jc]);
  }
}

// ---------------- graph MFMA: tmpb[b][i][0..415] = bf16( G[b] @ h[b] ) (k-pad zeros)
__global__ __launch_bounds__(256) void k_gmm(const float* __restrict__ G,
    const unsigned short* __restrict__ hT, unsigned short* __restrict__ tmpb) {
  __shared__ unsigned short a_sh[32 * 136];
  const int b = blockIdx.x >> 2;
  const int i0 = (blockIdx.x & 3) * 32;
  const int tid = threadIdx.x;
  for (int idx = tid; idx < 32 * 128; idx += 256) {
    int r = idx >> 7, j = idx & 127;
    int i = i0 + r;
    float v = (i < NODES && j < NODES) ? G[((size_t)b * NODES + i) * NODES + j] : 0.f;
    a_sh[r * 136 + j] = f2bf(v);
  }
  __syncthreads();
  const int lane = tid & 63, w = tid >> 6;
  const int lrow = lane & 15, lk = lane >> 4;
  const int rg = w & 1, nh = w >> 1;
  const int cbeg = nh * 13;
  f32x4 acc[13];
#pragma unroll
  for (int c = 0; c < 13; ++c) acc[c] = f32x4{0.f, 0.f, 0.f, 0.f};
  const unsigned short* ap = &a_sh[(rg * 16 + lrow) * 136 + lk * 8];
  const unsigned short* wp = &hT[((size_t)b * 416 + cbeg * 16 + lrow) * 128 + lk * 8];
  for (int ks = 0; ks < 4; ++ks) {
    s16x8 af = *reinterpret_cast<const s16x8*>(ap + ks * 32);
#pragma unroll
    for (int c = 0; c < 13; ++c) {
      s16x8 bf = *reinterpret_cast<const s16x8*>(wp + (size_t)c * 16 * 128 + ks * 32);
      acc[c] = __builtin_amdgcn_mfma_f32_16x16x32_bf16(af, bf, acc[c], 0, 0, 0);
    }
  }
  const int r0 = rg * 16 + lk * 4;
#pragma unroll
  for (int c = 0; c < 13; ++c) {
    int col = (cbeg + c) * 16 + lrow;
#pragma unroll
    for (int j = 0; j < 4; ++j) {
      int i = i0 + r0 + j;
      if (i < NODES)
        tmpb[((size_t)b * NODES + i) * 416 + col] = f2bf(acc[c][j]);
    }
  }
}

// ---------------- dense LN GEMM, bf16 A direct-global: out = LN(relu(A@W+b)+resid)
__global__ __launch_bounds__(256) void k_mgb_ln(
    const unsigned short* __restrict__ A, const unsigned short* __restrict__ Wt,
    const float* __restrict__ bias, const float* __restrict__ resid,
    const float* __restrict__ lns, const float* __restrict__ lnb,
    float* __restrict__ out) {
  __shared__ float ps_sh[32][2][2];
  const int tid = threadIdx.x;
  const size_t row0 = (size_t)blockIdx.x * 32;
  const int lane = tid & 63, w = tid >> 6;
  const int lrow = lane & 15, lk = lane >> 4;
  const int rg = w & 1, nh = w >> 1;
  const int cbeg = nh * 13;
  f32x4 acc[13];
#pragma unroll
  for (int c = 0; c < 13; ++c) acc[c] = f32x4{0.f, 0.f, 0.f, 0.f};
  const unsigned short* ap = &A[(row0 + rg * 16 + lrow) * 416 + lk * 8];
  const unsigned short* wp = &Wt[((size_t)(cbeg * 16) + lrow) * 416 + lk * 8];
  for (int ks = 0; ks < 13; ++ks) {
    s16x8 af = *reinterpret_cast<const s16x8*>(ap + ks * 32);
#pragma unroll
    for (int c = 0; c < 13; ++c) {
      s16x8 bf = *reinterpret_cast<const s16x8*>(wp + (size_t)c * 16 * 416 + ks * 32);
      acc[c] = __builtin_amdgcn_mfma_f32_16x16x32_bf16(af, bf, acc[c], 0, 0, 0);
    }
  }
  const int r0 = rg * 16 + lk * 4;
  float zs[4], zq[4];
#pragma unroll
  for (int j = 0; j < 4; ++j) { zs[j] = 0.f; zq[j] = 0.f; }
#pragma unroll
  for (int c = 0; c < 13; ++c) {
    int col = (cbeg + c) * 16 + lrow;
    bool cv = col < DD;
    float bv = cv ? bias[col] : 0.f;
#pragma unroll
    for (int j = 0; j < 4; ++j) {
      float z = 0.f;
      if (cv)
        z = fmaxf(acc[c][j] + bv, 0.f) + resid[(row0 + r0 + j) * (size_t)DD + col];
      acc[c][j] = z;
      zs[j] += z;
      zq[j] += z * z;
    }
  }
#pragma unroll
  for (int j = 0; j < 4; ++j) {
    zs[j] += __shfl_xor(zs[j], 1, 64); zq[j] += __shfl_xor(zq[j], 1, 64);
    zs[j] += __shfl_xor(zs[j], 2, 64); zq[j] += __shfl_xor(zq[j], 2, 64);
    zs[j] += __shfl_xor(zs[j], 4, 64); zq[j] += __shfl_xor(zq[j], 4, 64);
    zs[j] += __shfl_xor(zs[j], 8, 64); zq[j] += __shfl_xor(zq[j], 8, 64);
  }
  if (lrow == 0) {
#pragma unroll
    for (int j = 0; j < 4; ++j) {
      ps_sh[r0 + j][nh][0] = zs[j];
      ps_sh[r0 + j][nh][1] = zq[j];
    }
  }
  __syncthreads();
  float mu[4], rs[4];
#pragma unroll
  for (int j = 0; j < 4; ++j) {
    float s = ps_sh[r0 + j][0][0] + ps_sh[r0 + j][1][0];
    float q = ps_sh[r0 + j][0][1] + ps_sh[r0 + j][1][1];
    mu[j] = s * (1.0f / DD);
    float var = q * (1.0f / DD) - mu[j] * mu[j];
    rs[j] = 1.0f / sqrtf(var + 1e-5f);
  }
#pragma unroll
  for (int c = 0; c < 13; ++c) {
    int col = (cbeg + c) * 16 + lrow;
    if (col < DD) {
      float sc = lns[col], bo = lnb[col];
#pragma unroll
      for (int j = 0; j < 4; ++j)
        out[(row0 + r0 + j) * (size_t)DD + col] = (acc[c][j] - mu[j]) * rs[j] * sc + bo;
    }
  }
}

// ------------------------------- gf[b*100+i] = h2[b*118+i] + he[b*118+i]  (compact)
__global__ __launch_bounds__(256) void k_add_gf(const float* __restrict__ h2,
    const float* __restrict__ he, float* __restrict__ gf, int total) {
  int idx = blockIdx.x * 256 + threadIdx.x;
  if (idx >= total) return;
  int d = idx % DD;
  int bi = idx / DD;
  int i = bi % HH;
  int b = bi / HH;
  size_t src = ((size_t)b * NODES + i) * DD + d;
  gf[idx] = h2[src] + he[src];
}

// ---------------- one-shot weight prep (bf16 transposed+padded blobs)
__global__ __launch_bounds__(256) void k_prep_all(const float* __restrict__ gW,
    const float* __restrict__ afW, const float* __restrict__ Kw,
    const float* __restrict__ Qw, const float* __restrict__ icQw,
    const float* __restrict__ icKw, const float* __restrict__ Qb,
    const float* __restrict__ icQb, unsigned short* __restrict__ wbase,
    float* __restrict__ bias2) {
  int idx = blockIdx.x * 256 + threadIdx.x;
  const int SG = 416 * 416;   // 173056
  const int SK = 224 * 416;   // 93184
  if (idx < SG) {             // gW0t
    int n = idx / 416, k = idx - n * 416;
    wbase[idx] = (n < 400 && k < 400) ? f2bf(gW[(size_t)k * 400 + n]) : (unsigned short)0;
    return;
  }
  idx -= SG;
  if (idx < SG) {             // gW1t
    int n = idx / 416, k = idx - n * 416;
    wbase[173056 + idx] = (n < 400 && k < 400) ? f2bf(gW[160000 + (size_t)k * 400 + n]) : (unsigned short)0;
    return;
  }
  idx -= SG;
  if (idx < SG) {             // afWt
    int n = idx / 416, k = idx - n * 416;
    wbase[346112 + idx] = (n < 400 && k < 400) ? f2bf(afW[(size_t)k * 400 + n]) : (unsigned short)0;
    return;
  }
  idx -= SG;
  if (idx < SK) {             // Kwt [224 n][416 k]
    int n = idx / 416, k = idx - n * 416;
    wbase[519168 + idx] = (n < 200 && k < 400) ? f2bf(Kw[(size_t)k * 200 + n]) : (unsigned short)0;
    return;
  }
  idx -= SK;
  if (idx < SG) {             // Qqt [416 n][416 k]
    int n = idx / 416, k = idx - n * 416;
    unsigned short v = 0;
    if (k < 400) {
      if (n < 200) v = f2bf(Qw[(size_t)k * 200 + n]);
      else if (n >= 208 && n < 408) v = f2bf(icQw[(size_t)k * 200 + (n - 208)]);
    }
    wbase[612352 + idx] = v;
    return;
  }
  idx -= SG;
  if (idx < SK) {             // icKwB [416 d][224 a]
    int d = idx / 224, a = idx - d * 224;
    wbase[785408 + idx] = (d < 400 && a < 200) ? f2bf(icKw[(size_t)d * 200 + a]) : (unsigned short)0;
    return;
  }
  idx -= SK;
  if (idx < 416) {            // bias2
    float v = 0.f;
    if (idx < 200) v = Qb[idx];
    else if (idx >= 208 && idx < 408) v = icQb[idx - 208];
    bias2[idx] = v;
  }
}

// =================== fp32-A MFMA GEMM. EPI: 0 plain, 4 affine(relu+b+resid, in-place)+s-dot,
// 5 dual-output projection.
template<int KDIM, int KPAD, int NOUT, int EPI>
__global__ __launch_bounds__(256) void k_mg(
    const float* __restrict__ A, const unsigned short* __restrict__ Wt,
    const float* __restrict__ bias, const float* __restrict__ resid,
    const float* __restrict__ p, float* __restrict__ s_pre,
    float* __restrict__ out, float* __restrict__ out2) {
  constexpr int APITCH = KPAD + 8;
  constexpr int NF = (NOUT + 15) / 16;
  constexpr int NF0 = (NF + 1) / 2;
  constexpr int KS = KPAD / 32;
  constexpr int E4 = KDIM / 4;
  constexpr int PADN = KPAD - KDIM;
  __shared__ unsigned short a_sh[32 * APITCH];
  __shared__ float ps_sh[32][2];
  const int tid = threadIdx.x;
  const size_t row0 = (size_t)blockIdx.x * 32;
  for (int i = tid; i < 32 * E4; i += 256) {
    int r = i / E4, c4 = i - r * E4;
    const float4 v = *reinterpret_cast<const float4*>(&A[(row0 + r) * (size_t)KDIM + c4 * 4]);
    unsigned int lo = (unsigned int)f2bf(v.x) | ((unsigned int)f2bf(v.y) << 16);
    unsigned int hi = (unsigned int)f2bf(v.z) | ((unsigned int)f2bf(v.w) << 16);
    *reinterpret_cast<uint2*>(&a_sh[r * APITCH + c4 * 4]) = make_uint2(lo, hi);
  }
  for (int i = tid; i < 32 * PADN; i += 256) {
    int r = i / PADN, c = i - r * PADN;
    a_sh[r * APITCH + KDIM + c] = 0;
  }
  __syncthreads();
  const int lane = tid & 63, w = tid >> 6;
  const int lrow = lane & 15, lk = lane >> 4;
  const int rg = w & 1, nh = w >> 1;
  const int cbeg = nh * NF0;
  f32x4 acc[NF0];
#pragma unroll
  for (int c = 0; c < NF0; ++c) acc[c] = f32x4{0.f, 0.f, 0.f, 0.f};
  const unsigned short* ap = &a_sh[(rg * 16 + lrow) * APITCH + lk * 8];
  const unsigned short* wp = &Wt[((size_t)(cbeg * 16) + lrow) * KPAD + lk * 8];
  for (int ks = 0; ks < KS; ++ks) {
    s16x8 af = *reinterpret_cast<const s16x8*>(ap + ks * 32);
#pragma unroll
    for (int c = 0; c < NF0; ++c) {
      s16x8 bf = *reinterpret_cast<const s16x8*>(wp + (size_t)c * 16 * KPAD + ks * 32);
      acc[c] = __builtin_amdgcn_mfma_f32_16x16x32_bf16(af, bf, acc[c], 0, 0, 0);
    }
  }
  const int r0 = rg * 16 + lk * 4;
  if (EPI == 0) {
#pragma unroll
    for (int c = 0; c < NF0; ++c) {
      int col = (cbeg + c) * 16 + lrow;
      if (col < NOUT) {
#pragma unroll
        for (int j = 0; j < 4; ++j)
          out[(row0 + r0 + j) * (size_t)NOUT + col] = acc[c][j];
      }
    }
  } else if (EPI == 5) {
#pragma unroll
    for (int c = 0; c < NF0; ++c) {
      int col = (cbeg + c) * 16 + lrow;
      float bv = bias[col];
      if (col < 200) {
#pragma unroll
        for (int j = 0; j < 4; ++j)
          out[(row0 + r0 + j) * (size_t)AA + col] = acc[c][j] + bv;
      } else if (col >= 208 && col < 408) {
#pragma unroll
        for (int j = 0; j < 4; ++j)
          out2[(row0 + r0 + j) * (size_t)AA + (col - 208)] = acc[c][j] + bv;
      }
    }
  } else {  // EPI == 4: v = relu(x+b)+resid (in-place) ; s_pre[row] = dot(v, p[row/19]) * ATT_INV
    float spart[4] = {0.f, 0.f, 0.f, 0.f};
#pragma unroll
    for (int c = 0; c < NF0; ++c) {
      int col = (cbeg + c) * 16 + lrow;
      if (col < NOUT) {
        float bv = bias[col];
#pragma unroll
        for (int j = 0; j < 4; ++j) {
          size_t row = row0 + r0 + j;
          size_t o = row * (size_t)NOUT + col;
          float v = fmaxf(acc[c][j] + bv, 0.f) + resid[o];
          out[o] = v;
          spart[j] += v * p[(row / CATN) * (size_t)NOUT + col];
        }
      }
    }
#pragma unroll
    for (int j = 0; j < 4; ++j) {
      spart[j] += __shfl_xor(spart[j], 1, 64);
      spart[j] += __shfl_xor(spart[j], 2, 64);
      spart[j] += __shfl_xor(spart[j], 4, 64);
      spart[j] += __shfl_xor(spart[j], 8, 64);
    }
    if (lrow == 0) {
#pragma unroll
      for (int j = 0; j < 4; ++j) ps_sh[r0 + j][nh] = spart[j];
    }
    __syncthreads();
    if (tid < 32)
      s_pre[row0 + tid] = (ps_sh[tid][0] + ps_sh[tid][1]) * ATT_INV;
  }
}

// --------- alpha segment-softmax -> P bf16 [b][304][128]
__global__ __launch_bounds__(256) void k_palpha(const float* __restrict__ K,
    const float* __restrict__ Q, const int* __restrict__ cat,
    unsigned short* __restrict__ P) {
  __shared__ float q_sh[AA];
  __shared__ float a_sh[HH];
  __shared__ int c_sh[HH];
  __shared__ float smax[CATN], sden[CATN];
  const int bn = blockIdx.x;
  const int b = bn >> 4, n = bn & 15;
  const int tid = threadIdx.x;
  if (tid < AA) q_sh[tid] = Q[(size_t)bn * AA + tid];
  if (tid < HH) c_sh[tid] = cat[b * HH + tid];
  __syncthreads();
  if (tid < 2 * HH) {
    int h = tid >> 1, half = tid & 1;
    const float* kp = K + ((size_t)b * HH + h) * AA + half * 100;
    const float* qp = q_sh + half * 100;
    float s = 0.f;
#pragma unroll 4
    for (int a = 0; a < 100; ++a) s += kp[a] * qp[a];
    s += __shfl_xor(s, 1, 64);
    if (half == 0) a_sh[h] = s * ATT_INV;
  }
  __syncthreads();
  if (tid < CATN) {
    float m = -3.4e38f;
    for (int h = 0; h < HH; ++h)
      if (c_sh[h] == tid) m = fmaxf(m, a_sh[h]);
    smax[tid] = m;
  }
  __syncthreads();
  if (tid < HH) a_sh[tid] = expf(a_sh[tid] - smax[c_sh[tid]]);
  __syncthreads();
  if (tid < CATN) {
    float dsum = 0.f;
    for (int h = 0; h < HH; ++h)
      if (c_sh[h] == tid) dsum += a_sh[h];
    sden[tid] = dsum;
  }
  __syncthreads();
  if (tid < HH) a_sh[tid] = a_sh[tid] / sden[c_sh[tid]];
  __syncthreads();
  for (int idx = tid; idx < CATN * 128; idx += 256) {
    int c = idx >> 7, h = idx & 127;
    float v = (h < HH && c_sh[h] == c) ? a_sh[h] : 0.f;
    P[((size_t)b * 304 + n * CATN + c) * 128 + h] = f2bf(v);
  }
}

// --------- scatter GEMM: intra[b] = P[b] @ gf[b]  (via gfT), 16-row tiles, 2 waves
__global__ __launch_bounds__(128) void k_sc(const unsigned short* __restrict__ P,
    const unsigned short* __restrict__ gfT, float* __restrict__ intra) {
  const int b = blockIdx.x / CATN, t = blockIdx.x % CATN;
  const int tid = threadIdx.x;
  const int lane = tid & 63, w = tid >> 6;
  const int lrow = lane & 15, lk = lane >> 4;
  const int cbeg = w * 13;
  f32x4 acc[13];
#pragma unroll
  for (int c = 0; c < 13; ++c) acc[c] = f32x4{0.f, 0.f, 0.f, 0.f};
  const unsigned short* ap = &P[((size_t)b * 304 + t * 16 + lrow) * 128 + lk * 8];
  const unsigned short* wp = &gfT[((size_t)b * 416 + cbeg * 16 + lrow) * 128 + lk * 8];
  for (int ks = 0; ks < 4; ++ks) {
    s16x8 af = *reinterpret_cast<const s16x8*>(ap + ks * 32);
#pragma unroll
    for (int c = 0; c < 13; ++c) {
      s16x8 bf = *reinterpret_cast<const s16x8*>(wp + (size_t)c * 16 * 128 + ks * 32);
      acc[c] = __builtin_amdgcn_mfma_f32_16x16x32_bf16(af, bf, acc[c], 0, 0, 0);
    }
  }
  const int r0 = lk * 4;
#pragma unroll
  for (int c = 0; c < 13; ++c) {
    int col = (cbeg + c) * 16 + lrow;
    if (col < DD) {
#pragma unroll
      for (int j = 0; j < 4; ++j)
        intra[((size_t)b * 304 + t * 16 + r0 + j) * (size_t)DD + col] = acc[c][j];
    }
  }
}

// --------- masked softmax over 19 (s_pre precomputed) ; out = sum_c w*intra
__global__ __launch_bounds__(256) void k_final(const float* __restrict__ intra,
    const float* __restrict__ s_pre, const int* __restrict__ mask,
    float* __restrict__ out) {
  __shared__ float w_sh[CATN];
  const int bn = blockIdx.x;
  const int b = bn >> 4;
  const int tid = threadIdx.x;
  if (tid == 0) {
    float sv[CATN];
    float mx = -3.4e38f;
#pragma unroll
    for (int c = 0; c < CATN; ++c) {
      bool mk = (c == CATN - 1) || (mask[b * CATN + c] != 0);
      float s = mk ? s_pre[bn * CATN + c] : -3.4e38f;
      sv[c] = s;
      mx = fmaxf(mx, s);
    }
    float den = 0.f;
#pragma unroll
    for (int c = 0; c < CATN; ++c) {
      float e = (sv[c] <= -3.3e38f) ? 0.f : expf(sv[c] - mx);
      w_sh[c] = e;
      den += e;
    }
    float inv = 1.0f / den;
#pragma unroll
    for (int c = 0; c < CATN; ++c) w_sh[c] *= inv;
  }
  __syncthreads();
  const float* ib = intra + (size_t)bn * CATN * DD;
  for (int d = tid; d < DD; d += 256) {
    float o = 0.f;
#pragma unroll
    for (int c = 0; c < CATN; ++c) o += w_sh[c] * ib[(size_t)c * DD + d];
    out[(size_t)bn * DD + d] = o;
  }
}

// ============================================================================
extern "C" void kernel_launch(void* const* d_in, const int* in_sizes, int n_in,
                              void* d_out, int out_size, void* d_ws, size_t ws_size,
                              hipStream_t stream) {
  const float* hist  = (const float*)d_in[0];
  const float* cand  = (const float*)d_in[1];
  const float* G     = (const float*)d_in[2];
  const int*   cmask = (const int*)d_in[3];
  const int*   cidx  = (const int*)d_in[4];
  const float* proxy = (const float*)d_in[5];
  const float* gW    = (const float*)d_in[6];
  const float* gb    = (const float*)d_in[7];
  const float* lns   = (const float*)d_in[8];
  const float* lnb   = (const float*)d_in[9];
  const float* Kw    = (const float*)d_in[10];
  const float* Qw    = (const float*)d_in[11];
  const float* Qbb   = (const float*)d_in[12];
  const float* afW   = (const float*)d_in[13];
  const float* afb   = (const float*)d_in[14];
  const float* icKw  = (const float*)d_in[15];
  const float* icQw  = (const float*)d_in[16];
  const float* icQb  = (const float*)d_in[17];
  float* out = (float*)d_out;
  float* ws  = (float*)d_ws;

  // ---- workspace layout (float offsets) ----
  // SLOT0 @0 (3,020,800): he -> {P bf16, qbuf, qic, pbuf, s_pre}
  // SLOT1 @3,020,800: h1 -> h2(in-place) -> K [6400][200]
  // SLOT2 @6,041,600: tmpb bf16 [7552][416] -> gf [6400][400]
  // TB    @9,062,400: [64][416][128] bf16 (hT0 -> hT1 -> gfT)
  // intra @10,766,336: [19456][400]
  // bias2 @18,548,736 (416) ; wbase @18,549,152 (878,592 ushorts)
  float* he    = ws;
  float* s1    = ws + 3020800;
  float* s2f   = ws + 6041600;                  // gf region
  unsigned short* tmpb = (unsigned short*)(ws + 6041600);
  unsigned short* TB   = (unsigned short*)(ws + 9062400);
  float* intra = ws + 10766336;
  float* bias2 = ws + 18548736;
  unsigned short* wbase = (unsigned short*)(ws + 18549152);
  unsigned short* Pbuf = (unsigned short*)ws;   // SLOT0 reuse after he dead
  float* qbuf  = ws + 1245184;
  float* qic   = ws + 1449984;
  float* pbuf  = ws + 1654784;
  float* s_pre = ws + 2064384;
  float* Kbuf  = s1;                            // SLOT1 reuse after h2 dead
  unsigned short* gW0t  = wbase;                // [416][416]
  unsigned short* gW1t  = wbase + 173056;
  unsigned short* afWt  = wbase + 346112;
  unsigned short* Kwt   = wbase + 519168;       // [224][416]
  unsigned short* Qqt   = wbase + 612352;       // [416][416]
  unsigned short* icKwB = wbase + 785408;       // [416][224]

  // 0. weight prep
  k_prep_all<<<3434, 256, 0, stream>>>(gW, afW, Kw, Qw, icQw, icKw, Qbb, icQb, wbase, bias2);
  // 1. he
  k_concat_he<<<(BN * DD + 255) / 256, 256, 0, stream>>>(hist, proxy, he, BN * DD);
  // 2-4. GCN layer 0
  k_toT<NODES><<<448, 256, 0, stream>>>(he, TB);
  k_gmm<<<256, 256, 0, stream>>>(G, TB, tmpb);
  k_mgb_ln<<<BN / 32, 256, 0, stream>>>(tmpb, gW0t, gb, he, lns, lnb, s1);
  // 5-7. GCN layer 1 (h2 in-place over h1)
  k_toT<NODES><<<448, 256, 0, stream>>>(s1, TB);
  k_gmm<<<256, 256, 0, stream>>>(G, TB, tmpb);
  k_mgb_ln<<<BN / 32, 256, 0, stream>>>(tmpb, gW1t, gb + DD, s1, lns + DD, lnb + DD, s1);
  // 8. gf = (h2 + he)[:, :HH] compact -> SLOT2
  k_add_gf<<<(BH * DD + 255) / 256, 256, 0, stream>>>(s1, he, s2f, BH * DD);
  // 9. gfT
  k_toT<HH><<<448, 256, 0, stream>>>(s2f, TB);
  // 10. K = gf @ Kw -> SLOT1
  k_mg<400, 416, 200, 0><<<BH / 32, 256, 0, stream>>>(s2f, Kwt, nullptr, nullptr, nullptr, nullptr, Kbuf, nullptr);
  // 11. dual projection Q/qic
  k_mg<400, 416, 416, 5><<<BB * NN / 32, 256, 0, stream>>>(cand, Qqt, bias2, nullptr, nullptr, nullptr, qbuf, qic);
  // 12. p = qic @ icKw^T
  k_mg<200, 224, 400, 0><<<BB * NN / 32, 256, 0, stream>>>(qic, icKwB, nullptr, nullptr, nullptr, nullptr, pbuf, nullptr);
  // 13. alpha -> P
  k_palpha<<<BB * NN, 256, 0, stream>>>(Kbuf, qbuf, cidx, Pbuf);
  // 14. intra = P @ gf (MFMA)
  k_sc<<<BB * CATN, 128, 0, stream>>>(Pbuf, TB, intra);
  // 15. affine in-place + fused s-dot
  k_mg<400, 416, 400, 4><<<BB * NN * CATN / 32, 256, 0, stream>>>(intra, afWt, afb, intra, pbuf, s_pre, intra, nullptr);
  // 16. final softmax + weighted sum
  k_final<<<BB * NN, 256, 0, stream>>>(intra, s_pre, cmask, out);
}